// Round 2
// baseline (87.283 us; speedup 1.0000x reference)
//
#include <hip/hip_runtime.h>

#define KS 5
#define BETA 15.0f
#define LOG2E 1.4426950408889634f
#define LN2 0.6931471805599453f

// x: (B=4, C=64, H=128, W=128) fp32, weight_y: (64, 5, 5) fp32
// out: (4, 64, 128, 128) fp32
// y = logsumexp over 25 taps of (w + x_pad)*BETA, / BETA. Zero padding:
// out-of-range x contributes tap value w*BETA (x=0), NOT skipped.

__global__ __launch_bounds__(256) void morph_soft_dilate(
    const float* __restrict__ x,
    const float* __restrict__ wy,
    float* __restrict__ out)
{
    __shared__ float w_s[32];  // 25 used, pre-scaled by BETA*LOG2E

    const int tid = threadIdx.x;
    const int gid = blockIdx.x * 256 + tid;

    // 128*128 = 16384 pixels per (b,c) plane = 64 blocks of 256.
    const int plane = blockIdx.x >> 6;       // b*64 + c
    const int c = plane & 63;

    if (tid < 25) {
        w_s[tid] = wy[c * 25 + tid] * (BETA * LOG2E);
    }
    __syncthreads();

    const int pix = gid & (128 * 128 - 1);
    const int h = pix >> 7;
    const int w = pix & 127;
    const float* xp = x + (size_t)plane * (128 * 128);
    const float scale = BETA * LOG2E;

    // Pass 1: compute u_t = (x_t)*scale + w'_t for all 25 taps, track max.
    float u[25];
    float m = -3.0e38f;
#pragma unroll
    for (int i = 0; i < KS; ++i) {
        const int hh = h + i - 2;
        const bool hv = ((unsigned)hh < 128u);
        const int rowbase = hh * 128;
#pragma unroll
        for (int j = 0; j < KS; ++j) {
            const int ww = w + j - 2;
            const bool v = hv && ((unsigned)ww < 128u);
            const float xv = v ? xp[rowbase + ww] : 0.0f;
            const float ui = fmaf(xv, scale, w_s[i * KS + j]);
            u[i * KS + j] = ui;
            m = fmaxf(m, ui);
        }
    }

    // Pass 2: sum 2^(u - m); u - m <= 0 and >= ~-260 -> exp2 safe (flushes to 0).
    float s = 0.0f;
#pragma unroll
    for (int t = 0; t < 25; ++t) {
        s += __builtin_amdgcn_exp2f(u[t] - m);
    }

    // y = ln2 * (m + log2(s)) / BETA   (__builtin_amdgcn_logf is v_log_f32 = log2)
    const float y = (m + __builtin_amdgcn_logf(s)) * (LN2 / BETA);
    out[gid] = y;
}

extern "C" void kernel_launch(void* const* d_in, const int* in_sizes, int n_in,
                              void* d_out, int out_size, void* d_ws, size_t ws_size,
                              hipStream_t stream) {
    const float* x  = (const float*)d_in[0];
    const float* wy = (const float*)d_in[1];
    float* out      = (float*)d_out;

    const int total = out_size;              // 4*64*128*128 = 4194304
    const int blocks = total / 256;          // 16384
    morph_soft_dilate<<<blocks, 256, 0, stream>>>(x, wy, out);
}

// Round 3
// 74.076 us; speedup vs baseline: 1.1783x; 1.1783x over previous
//
#include <hip/hip_runtime.h>

#define KS 5
#define BETA 15.0f
#define LOG2E 1.4426950408889634f
#define LN2 0.6931471805599453f
#define SHIFT 16.0f

// x: (B=4, C=64, H=128, W=128) fp32, weight_y: (64,5,5) fp32 -> out same as x.
// y = logsumexp_{25 taps}((w + x_pad)*BETA)/BETA, zero padding.
// Exp-domain restructure: E = 2^(x*scale - 16) once per input pixel,
// W_t = 2^(w_t*scale) per channel, y = (log2(sum W_t*E_t) + 16)*ln2/BETA.

#define TROWS 8          // output rows per block
#define LROWS 12         // TROWS + 4 halo
#define LPITCH 136       // floats per LDS row: 4 left pad + 128 + 4 right pad
#define PADV 1.52587890625e-05f   // 2^-16, E-value of zero-padded x

__global__ __launch_bounds__(256) void morph_soft_dilate(
    const float* __restrict__ x,
    const float* __restrict__ wy,
    float* __restrict__ out)
{
    __shared__ float e_s[LROWS * LPITCH];   // 6528 B
    __shared__ float w_s[28];

    const int tid   = threadIdx.x;
    const int plane = blockIdx.x >> 4;          // b*64 + c
    const int h0    = (blockIdx.x & 15) * TROWS;
    const int c     = plane & 63;
    const float scale = BETA * LOG2E;

    if (tid < 25) w_s[tid] = __builtin_amdgcn_exp2f(wy[c * 25 + tid] * scale);
    if (tid >= 25 && tid < 28) w_s[tid] = 0.0f;

    const float* xp = x + (size_t)plane * (128 * 128);

    // ---- Stage E into LDS: 12 rows x 34 float4-slots = 408 slots ----
    // LDS col layout: index = xcol + 4 (cols -4..131). Slot q covers xcols
    // (q-1)*4 .. (q-1)*4+3 for q in [1,32]; q==0 / q==33 are padding.
#pragma unroll
    for (int it = 0; it < 2; ++it) {
        const int s = tid + it * 256;
        if (s < LROWS * 34) {
            const int r = s / 34;
            const int q = s - r * 34;
            float4 ev = make_float4(PADV, PADV, PADV, PADV);
            const int xrow = h0 + r - 2;
            if (q >= 1 && q <= 32 && (unsigned)xrow < 128u) {
                const float4 xv = *(const float4*)(xp + xrow * 128 + (q - 1) * 4);
                ev.x = __builtin_amdgcn_exp2f(fmaf(xv.x, scale, -SHIFT));
                ev.y = __builtin_amdgcn_exp2f(fmaf(xv.y, scale, -SHIFT));
                ev.z = __builtin_amdgcn_exp2f(fmaf(xv.z, scale, -SHIFT));
                ev.w = __builtin_amdgcn_exp2f(fmaf(xv.w, scale, -SHIFT));
            }
            *(float4*)(e_s + r * LPITCH + q * 4) = ev;
        }
    }
    __syncthreads();

    // ---- Per-thread weights in registers (broadcast reads from LDS) ----
    float w_r[28];
#pragma unroll
    for (int t = 0; t < 7; ++t) {
        const float4 wv = *(const float4*)(w_s + t * 4);
        w_r[t * 4 + 0] = wv.x; w_r[t * 4 + 1] = wv.y;
        w_r[t * 4 + 2] = wv.z; w_r[t * 4 + 3] = wv.w;
    }

    // ---- Compute 4 pixels per thread ----
    const int tx = tid & 31;        // 32 threads x 4 px = 128 cols
    const int ty = tid >> 5;        // 8 rows
    const int wcol = tx * 4;

    float acc0 = 0.0f, acc1 = 0.0f, acc2 = 0.0f, acc3 = 0.0f;
#pragma unroll
    for (int i = 0; i < KS; ++i) {
        const float* row = e_s + (ty + i) * LPITCH + wcol;
        float f[12];
        const float4 a = *(const float4*)(row);
        const float4 b = *(const float4*)(row + 4);
        const float4 cc = *(const float4*)(row + 8);
        f[0]=a.x; f[1]=a.y; f[2]=a.z;  f[3]=a.w;
        f[4]=b.x; f[5]=b.y; f[6]=b.z;  f[7]=b.w;
        f[8]=cc.x; f[9]=cc.y; f[10]=cc.z; f[11]=cc.w;
#pragma unroll
        for (int j = 0; j < KS; ++j) {
            const float wv = w_r[i * KS + j];
            acc0 = fmaf(wv, f[j + 2], acc0);
            acc1 = fmaf(wv, f[j + 3], acc1);
            acc2 = fmaf(wv, f[j + 4], acc2);
            acc3 = fmaf(wv, f[j + 5], acc3);
        }
    }

    const float k = LN2 / BETA;
    float4 o;
    o.x = (__builtin_amdgcn_logf(acc0) + SHIFT) * k;
    o.y = (__builtin_amdgcn_logf(acc1) + SHIFT) * k;
    o.z = (__builtin_amdgcn_logf(acc2) + SHIFT) * k;
    o.w = (__builtin_amdgcn_logf(acc3) + SHIFT) * k;

    *(float4*)(out + (size_t)plane * (128 * 128) + (h0 + ty) * 128 + wcol) = o;
}

extern "C" void kernel_launch(void* const* d_in, const int* in_sizes, int n_in,
                              void* d_out, int out_size, void* d_ws, size_t ws_size,
                              hipStream_t stream) {
    const float* x  = (const float*)d_in[0];
    const float* wy = (const float*)d_in[1];
    float* out      = (float*)d_out;

    // 256 planes x 16 row-blocks; 256 threads = 8 rows x (32 thr x 4 px)
    morph_soft_dilate<<<256 * 16, 256, 0, stream>>>(x, wy, out);
}

// Round 4
// 73.956 us; speedup vs baseline: 1.1802x; 1.0016x over previous
//
#include <hip/hip_runtime.h>

#define KS 5
#define BETA 15.0f
#define LOG2E 1.4426950408889634f
#define LN2 0.6931471805599453f
#define SHIFT 16.0f

// y = logsumexp_{25 taps}((w + x_pad)*BETA)/BETA, zero padding.
// Exp-domain: E = 2^(x*scale - 16) (pad x=0 -> E=2^-16 exactly),
// W_t = 2^(w_t*scale), y = (log2(sum W_t*E_t) + 16)*ln2/BETA.
// Thread = 4 cols x 4 rows strip; 5x8 E-window slides down in registers.
// Block 256 = 32 colgroups x 8 strips -> 32 rows; grid = 256 planes x 4.

__global__ __launch_bounds__(256) void morph_soft_dilate(
    const float* __restrict__ x,
    const float* __restrict__ wy,
    float* __restrict__ out)
{
    __shared__ float w_s[25];

    const int tid   = threadIdx.x;
    const int plane = blockIdx.x >> 2;         // b*64 + c
    const int rb    = blockIdx.x & 3;
    const int c     = plane & 63;
    const float scale = BETA * LOG2E;

    if (tid < 25) w_s[tid] = __builtin_amdgcn_exp2f(wy[c * 25 + tid] * scale);
    __syncthreads();

    float W[25];
#pragma unroll
    for (int t = 0; t < 25; ++t) W[t] = w_s[t];

    const int tx = tid & 31;          // colgroup: cols 4tx..4tx+3
    const int ty = tid >> 5;          // strip 0..7
    const int wc = tx * 4;
    const int h0 = rb * 32 + ty * 4;  // first output row
    const float* xp = x + (size_t)plane * 16384;
    float* op = out + (size_t)plane * 16384;
    const bool lok = (tx > 0);
    const bool rok = (tx < 31);

    float win[5][8];  // E-values for cols wc-2..wc+5, 5 input rows

    auto loadE = [&](int row, float* E) {
        float xv[8] = {0, 0, 0, 0, 0, 0, 0, 0};
        if ((unsigned)row < 128u) {
            const float* rp = xp + row * 128 + wc;
            if (lok) { const float2 a = *(const float2*)(rp - 2); xv[0] = a.x; xv[1] = a.y; }
            const float4 b = *(const float4*)rp;
            xv[2] = b.x; xv[3] = b.y; xv[4] = b.z; xv[5] = b.w;
            if (rok) { const float2 cv = *(const float2*)(rp + 4); xv[6] = cv.x; xv[7] = cv.y; }
        }
#pragma unroll
        for (int k = 0; k < 8; ++k)
            E[k] = __builtin_amdgcn_exp2f(fmaf(xv[k], scale, -SHIFT));
    };

    // Prologue: input rows h0-2 .. h0+1 into win[0..3]
#pragma unroll
    for (int k = 0; k < 4; ++k) loadE(h0 - 2 + k, win[k]);

    const float kk = LN2 / BETA;
#pragma unroll
    for (int s = 0; s < 4; ++s) {
        loadE(h0 + 2 + s, win[(4 + s) % 5]);

        float a0 = 0.0f, a1 = 0.0f, a2 = 0.0f, a3 = 0.0f;
#pragma unroll
        for (int i = 0; i < KS; ++i) {
            const float* e = win[(s + i) % 5];
#pragma unroll
            for (int j = 0; j < KS; ++j) {
                const float wv = W[i * KS + j];
                a0 = fmaf(wv, e[j + 0], a0);
                a1 = fmaf(wv, e[j + 1], a1);
                a2 = fmaf(wv, e[j + 2], a2);
                a3 = fmaf(wv, e[j + 3], a3);
            }
        }

        float4 o;
        o.x = (__builtin_amdgcn_logf(a0) + SHIFT) * kk;
        o.y = (__builtin_amdgcn_logf(a1) + SHIFT) * kk;
        o.z = (__builtin_amdgcn_logf(a2) + SHIFT) * kk;
        o.w = (__builtin_amdgcn_logf(a3) + SHIFT) * kk;
        *(float4*)(op + (h0 + s) * 128 + wc) = o;
    }
}

extern "C" void kernel_launch(void* const* d_in, const int* in_sizes, int n_in,
                              void* d_out, int out_size, void* d_ws, size_t ws_size,
                              hipStream_t stream) {
    const float* x  = (const float*)d_in[0];
    const float* wy = (const float*)d_in[1];
    float* out      = (float*)d_out;

    // 256 planes x 4 row-blocks of 32 rows
    morph_soft_dilate<<<256 * 4, 256, 0, stream>>>(x, wy, out);
}